// Round 10
// baseline (163.011 us; speedup 1.0000x reference)
//
#include <hip/hip_runtime.h>
#include <math.h>

// r10: r8 topology (8 waves x 32-row strips, 2-way A-frag reuse) + latency
// fixes. r9 post-mortem: 16-row strips halved A-reuse -> LDS-pipe-bound got
// worse despite 2x occupancy. r10: K0 PRE-SWIZZLES weights into chunk-ready
// LDS layout (staging = linear copy); FFN double-buffered 32u chunks with
// loads for c+1 issued before compute of c (1 barrier/chunk); setprio around
// MFMA clusters. All fragment math verbatim r8 (proven).

#define SQRT_D 11.313708498984761f
#define PE_C   0.14391156831212787f
#define INV_SQRT_DK 0.17677669529663687f
#define XF(j,d) (((j) << 7) + ((d) ^ (((j) & 15) << 2)))

typedef _Float16 f16x8 __attribute__((ext_vector_type(8)));
typedef float    f32x4 __attribute__((ext_vector_type(4)));

#define MFMA(a, b, c) __builtin_amdgcn_mfma_f32_16x16x32_f16((a), (b), (c), 0, 0, 0)

__device__ __forceinline__ unsigned pack2(float a, float b) {
  union { _Float16 h; unsigned short s; } ua, ub;
  ua.h = (_Float16)a; ub.h = (_Float16)b;
  return (unsigned)ua.s | ((unsigned)ub.s << 16);
}

__device__ __forceinline__ unsigned bperm(int addr, unsigned v) {
  return (unsigned)__builtin_amdgcn_ds_bpermute(addr, (int)v);
}

__device__ __forceinline__ f16x8 u4f16x8(unsigned u0, unsigned u1, unsigned u2, unsigned u3) {
  union { unsigned u[4]; f16x8 f; } x;
  x.u[0] = u0; x.u[1] = u1; x.u[2] = u2; x.u[3] = u3;
  return x.f;
}

// B-frag from two C/D tiles (r6-r9 verified).
__device__ __forceinline__ f16x8 make_bfrag(f32x4 cA, f32x4 cB, int aLo, int aHi, int hiSel) {
  unsigned a0 = pack2(cA[0], cA[1]), a1 = pack2(cA[2], cA[3]);
  unsigned b0 = pack2(cB[0], cB[1]), b1 = pack2(cB[2], cB[3]);
  unsigned lA0 = bperm(aLo, a0), lA1 = bperm(aLo, a1);
  unsigned hA0 = bperm(aHi, a0), hA1 = bperm(aHi, a1);
  unsigned lB0 = bperm(aLo, b0), lB1 = bperm(aLo, b1);
  unsigned hB0 = bperm(aHi, b0), hB1 = bperm(aHi, b1);
  return u4f16x8(hiSel ? lB0 : lA0, hiSel ? lB1 : lA1,
                 hiSel ? hB0 : hA0, hiSel ? hB1 : hA1);
}

// ---------------- K0: f32 -> f16 + pre-swizzle into staged layouts ----------
// W16 layout (f16 idx): [0:65536) w1L0 | [65536:131072) w2L0 | [131072:196608)
// w1L1 | [196608:262144) w2L1 | [262144:311296) kvq L1 (k|v|q, per-head 4096)
// | [311296:327680) ow L1 linear.
// w1 chunk c (32u): dst c*4096 + row*128 + gs*8+e holds src granule g=gs^(row&15).
// w2 chunk c (32u): dst c*4096 + d*32 + gs*8+e holds src granule g=gs^(d&3).
struct P0 { const float *qw, *kw, *vw, *ow, *w1, *w2; _Float16* dst; };

__global__ __launch_bounds__(256) void convswz(P0 p) {
  const int i = blockIdx.x * 256 + threadIdx.x;   // 1280 blocks -> 327680
  const float* src; int sidx;
  if (i < 262144) {
    const int L = i >> 17;
    const int r = i & 131071;
    if (r < 65536) {          // w1
      const int c = (r >> 12) & 15, row = (r >> 7) & 31, gs = (r >> 3) & 15, e = r & 7;
      const int g = gs ^ (row & 15);
      sidx = L * 65536 + (c * 32 + row) * 128 + g * 8 + e;
      src = p.w1;
    } else {                  // w2
      const int j = r - 65536;
      const int c = (j >> 12) & 15, row = (j >> 5) & 127, gs = (j >> 3) & 3, e = j & 7;
      const int g = gs ^ (row & 3);
      sidx = L * 65536 + row * 512 + c * 32 + g * 8 + e;
      src = p.w2;
    }
  } else if (i < 311296) {    // kvq layer-1
    const int j = i - 262144;
    const int m = j >> 14;    // 0=k 1=v 2=q
    const int rem = j & 16383;
    const int h = (rem >> 12) & 3, row = (rem >> 7) & 31, gs = (rem >> 3) & 15, e = rem & 7;
    const int g = gs ^ (row & 15);
    sidx = 16384 + (h * 32 + row) * 128 + g * 8 + e;
    src = (m == 0) ? p.kw : ((m == 1) ? p.vw : p.qw);
  } else {                    // ow layer-1 linear
    sidx = 16384 + (i - 311296);
    src = p.ow;
  }
  p.dst[i] = (_Float16)src[sidx];
}

// ---------------- K1: prep (verified r3) ----------------
struct P1 {
  const float* src; const int* t;
  const float* fc_w; const float* fc_b; const float* gc_w; const float* gc_b;
  const float* ln_w; const float* ln_b;
  const float* n1a; const float* n1b;
  const float* vw; const float* vb; const float* ow; const float* ob;
  float* x0; float* a0;
};

__device__ __forceinline__ float rowReduceSum(float v, volatile float* red, int d) {
#pragma unroll
  for (int off = 32; off > 0; off >>= 1) v += __shfl_xor(v, off, 64);
  if ((d & 63) == 0) red[d >> 6] = v;
  __syncthreads();
  float r = red[0] + red[1];
  __syncthreads();
  return r;
}

__device__ __forceinline__ float dot128s(const float* __restrict__ w,
                                         const float* __restrict__ xs) {
  const float4* __restrict__ w4 = (const float4*)w;
  const float4* __restrict__ x4 = (const float4*)xs;
  float a0 = 0.f, a1 = 0.f, a2 = 0.f, a3 = 0.f;
#pragma unroll
  for (int k = 0; k < 32; k += 4) {
    float4 xv0 = x4[k + 0], xv1 = x4[k + 1], xv2 = x4[k + 2], xv3 = x4[k + 3];
    float4 wv0 = w4[k + 0], wv1 = w4[k + 1], wv2 = w4[k + 2], wv3 = w4[k + 3];
    a0 = fmaf(wv0.w, xv0.w, fmaf(wv0.z, xv0.z, fmaf(wv0.y, xv0.y, fmaf(wv0.x, xv0.x, a0))));
    a1 = fmaf(wv1.w, xv1.w, fmaf(wv1.z, xv1.z, fmaf(wv1.y, xv1.y, fmaf(wv1.x, xv1.x, a1))));
    a2 = fmaf(wv2.w, xv2.w, fmaf(wv2.z, xv2.z, fmaf(wv2.y, xv2.y, fmaf(wv2.x, xv2.x, a2))));
    a3 = fmaf(wv3.w, xv3.w, fmaf(wv3.z, xv3.z, fmaf(wv3.y, xv3.y, fmaf(wv3.x, xv3.x, a3))));
  }
  return (a0 + a1) + (a2 + a3);
}

__global__ __launch_bounds__(256) void prep(P1 p) {
  __shared__ __align__(16) float s_src[2][16];
  __shared__ __align__(16) float s_x2[2][128];
  __shared__ __align__(16) float s_y[2][128];
  __shared__ float s_red[2][2];

  const int tid = threadIdx.x;
  const int rl  = tid >> 7;
  const int d   = tid & 127;
  const int row = blockIdx.x * 2 + rl;
  volatile float* red = s_red[rl];

  if (d < 14) s_src[rl][d + 1] = p.src[row * 14 + d];
  if (d == 14) { s_src[rl][0] = 0.f; s_src[rl][15] = 0.f; }
  __syncthreads();

  const float fw0 = p.fc_w[3*d+0], fw1 = p.fc_w[3*d+1], fw2 = p.fc_w[3*d+2];
  const float gw0 = p.gc_w[3*d+0], gw1 = p.gc_w[3*d+1], gw2 = p.gc_w[3*d+2];
  const float fb = p.fc_b[d], gb = p.gc_b[d];
  float g = 0.f;
#pragma unroll
  for (int m = 0; m < 14; ++m) {
    float xm1 = s_src[rl][m], x0v = s_src[rl][m+1], xp1 = s_src[rl][m+2];
    float f  = fmaf(fw2, xp1, fmaf(fw1, x0v, fmaf(fw0, xm1, fb)));
    float ga = fmaf(gw2, xp1, fmaf(gw1, x0v, fmaf(gw0, xm1, gb)));
    g = fmaf(f, 1.f / (1.f + expf(-ga)), g);
  }
  g *= (1.f / 14.f);

  float mu = rowReduceSum(g, red, d) * (1.f / 128.f);
  float cg = g - mu;
  float var = rowReduceSum(cg * cg, red, d) * (1.f / 128.f);
  float x = fmaf(p.ln_w[d], cg * rsqrtf(var + 1e-5f), p.ln_b[d]);

  const int tval = *p.t;
  {
    int i2 = d >> 1;
    float arg = (float)tval * expf((float)i2 * -PE_C);
    float pe = (d & 1) ? cosf(arg) : sinf(arg);
    x = fmaf(x, SQRT_D, pe);
  }
  p.x0[row * 128 + d] = x;

  float mu1 = rowReduceSum(x, red, d) * (1.f / 128.f);
  float c1 = x - mu1;
  float v1 = rowReduceSum(c1 * c1, red, d) * (1.f / 127.f);
  s_x2[rl][d] = fmaf(p.n1a[d], c1 / (sqrtf(v1) + 1e-6f), p.n1b[d]);
  __syncthreads();

  float y = p.vb[d] + dot128s(p.vw + d * 128, s_x2[rl]);
  s_y[rl][d] = y;
  __syncthreads();
  p.a0[row * 128 + d] = p.ob[d] + dot128s(p.ow + d * 128, s_y[rl]);
}

// ---------------- K2: per-batch MFMA megakernel ----------------
struct P2 {
  const float* x0; const float* a0;
  const _Float16* wff;    // preswizzled FFN weights (262144 f16)
  const _Float16* wkvq;   // preswizzled L1 kvq (49152 f16)
  const _Float16* wow;    // linear L1 ow (16384 f16)
  const float *qb, *kb, *vb, *ob;
  const float *n1a, *n1b, *n2a, *n2b;
  const float *b1, *b2;
  const float *fna, *fnb, *out_w, *out_b;
  float* out;
};

// norm (ddof=1, eps on std) of 16 rows (pass nt) -> B-frags out[4]. (r8)
__device__ __forceinline__ void build_x2_pass(const float* sX, int strip, int nt, int l,
    const float* __restrict__ na, const float* __restrict__ nb, f16x8 out[4]) {
  const int l15 = l & 15, q = l >> 4;
  const int row = strip + nt * 16 + l15;
  float sum = 0.f, sq = 0.f;
#pragma unroll
  for (int c4 = 0; c4 < 8; ++c4) {
    f32x4 v = *(const f32x4*)&sX[XF(row, q * 32 + c4 * 4)];
#pragma unroll
    for (int e = 0; e < 4; ++e) { sum += v[e]; sq = fmaf(v[e], v[e], sq); }
  }
  sum += __shfl_xor(sum, 16); sum += __shfl_xor(sum, 32);
  sq  += __shfl_xor(sq, 16);  sq  += __shfl_xor(sq, 32);
  const float mu = sum * (1.f / 128.f);
  const float var = fmaf(-sum, mu, sq) * (1.f / 127.f);
  const float inv = 1.f / (sqrtf(var) + 1e-6f);
#pragma unroll
  for (int kt = 0; kt < 4; ++kt) {
    const int d0 = kt * 32 + q * 8;
    f32x4 xA = *(const f32x4*)&sX[XF(row, d0)];
    f32x4 xB = *(const f32x4*)&sX[XF(row, d0 + 4)];
    f32x4 nA = *(const f32x4*)&na[d0], nB = *(const f32x4*)&na[d0 + 4];
    f32x4 bA = *(const f32x4*)&nb[d0], bB = *(const f32x4*)&nb[d0 + 4];
    float v0 = fmaf(nA[0] * inv, xA[0] - mu, bA[0]);
    float v1 = fmaf(nA[1] * inv, xA[1] - mu, bA[1]);
    float v2 = fmaf(nA[2] * inv, xA[2] - mu, bA[2]);
    float v3 = fmaf(nA[3] * inv, xA[3] - mu, bA[3]);
    float v4 = fmaf(nB[0] * inv, xB[0] - mu, bB[0]);
    float v5 = fmaf(nB[1] * inv, xB[1] - mu, bB[1]);
    float v6 = fmaf(nB[2] * inv, xB[2] - mu, bB[2]);
    float v7 = fmaf(nB[3] * inv, xB[3] - mu, bB[3]);
    out[kt] = u4f16x8(pack2(v0, v1), pack2(v2, v3), pack2(v4, v5), pack2(v6, v7));
  }
}

// FFN: 16 chunks of 32u, double-buffered pre-swizzled staging, T14 early loads.
// buf b at aux + b*8192 (f16): [0:4096) w1c, [4096:8192) w2c.
__device__ __forceinline__ void ffn_phase(float* sX, _Float16* aux, int t,
    int strip, int l, const float* __restrict__ na, const float* __restrict__ nb,
    const _Float16* __restrict__ w1s, const float* __restrict__ b1,
    const _Float16* __restrict__ w2s, const float* __restrict__ b2,
    int aLo, int aHi, int hiSel) {
  const int l15 = l & 15, lg = l >> 4;
  f16x8 x2f[4][2];
#pragma unroll
  for (int nt = 0; nt < 2; ++nt) {
    f16x8 tmp[4];
    build_x2_pass(sX, strip, nt, l, na, nb, tmp);
#pragma unroll
    for (int kt = 0; kt < 4; ++kt) x2f[kt][nt] = tmp[kt];
  }
  // prologue: load chunk 0
  f16x8 pre1 = *(const f16x8*)(w1s + t * 8);
  f16x8 pre2 = *(const f16x8*)(w2s + t * 8);
  __syncthreads();   // phase entry: prior phase's aux reads done
#pragma unroll 1
  for (int c = 0; c < 16; ++c) {
    _Float16* buf = aux + (c & 1) * 8192;
    *(f16x8*)(buf + t * 8) = pre1;
    *(f16x8*)(buf + 4096 + t * 8) = pre2;
    __syncthreads();
    if (c < 15) {   // issue next chunk's loads before compute (latency hides)
      pre1 = *(const f16x8*)(w1s + (c + 1) * 4096 + t * 8);
      pre2 = *(const f16x8*)(w2s + (c + 1) * 4096 + t * 8);
    }
    // H = relu(w1c @ x2 + b1c)
    f32x4 hacc[2][2];
#pragma unroll
    for (int mt = 0; mt < 2; ++mt) {
      f32x4 b = *(const f32x4*)&b1[c * 32 + mt * 16 + lg * 4];
      hacc[mt][0] = b; hacc[mt][1] = b;
    }
    __builtin_amdgcn_s_setprio(1);
#pragma unroll
    for (int mt = 0; mt < 2; ++mt)
#pragma unroll
      for (int kt = 0; kt < 4; ++kt) {
        f16x8 a = *(const f16x8*)(buf + (mt * 16 + l15) * 128 + (((kt * 4 + lg) ^ l15) << 3));
        hacc[mt][0] = MFMA(a, x2f[kt][0], hacc[mt][0]);
        hacc[mt][1] = MFMA(a, x2f[kt][1], hacc[mt][1]);
      }
    __builtin_amdgcn_s_setprio(0);
#pragma unroll
    for (int mt = 0; mt < 2; ++mt)
#pragma unroll
      for (int nt = 0; nt < 2; ++nt)
#pragma unroll
        for (int e = 0; e < 4; ++e) hacc[mt][nt][e] = fmaxf(hacc[mt][nt][e], 0.f);
    f16x8 hf0 = make_bfrag(hacc[0][0], hacc[1][0], aLo, aHi, hiSel);
    f16x8 hf1 = make_bfrag(hacc[0][1], hacc[1][1], aLo, aHi, hiSel);
    const _Float16* w2c = buf + 4096;
#pragma unroll 1
    for (int dh = 0; dh < 2; ++dh) {
      f32x4 oacc[4][2];
#pragma unroll
      for (int mt = 0; mt < 4; ++mt) {
        if (c == 0) {
          f32x4 b = *(const f32x4*)&b2[dh * 64 + mt * 16 + lg * 4];
          oacc[mt][0] = b; oacc[mt][1] = b;
        } else {
          f32x4 z = {0.f, 0.f, 0.f, 0.f};
          oacc[mt][0] = z; oacc[mt][1] = z;
        }
      }
      __builtin_amdgcn_s_setprio(1);
#pragma unroll
      for (int mt = 0; mt < 4; ++mt) {
        const int row = dh * 64 + mt * 16 + l15;
        f16x8 a = *(const f16x8*)(w2c + row * 32 + ((lg ^ (row & 3)) << 3));
        oacc[mt][0] = MFMA(a, hf0, oacc[mt][0]);
        oacc[mt][1] = MFMA(a, hf1, oacc[mt][1]);
      }
      __builtin_amdgcn_s_setprio(0);
#pragma unroll
      for (int mt = 0; mt < 4; ++mt)
#pragma unroll
        for (int nt = 0; nt < 2; ++nt) {
          const int row = strip + nt * 16 + l15;
          float* dst = &sX[XF(row, dh * 64 + mt * 16 + lg * 4)];
          f32x4 v = *(const f32x4*)dst;
          v += oacc[mt][nt];
          *(f32x4*)dst = v;
        }
    }
  }
}

__global__ __launch_bounds__(512) void batchk(P2 p) {
  __shared__ __align__(16) float sX[32768];        // 128 KB, XF-swizzled
  __shared__ __align__(16) _Float16 sAux[16384];   // 32 KB: dbuf / staged / K+VT

  const int t = threadIdx.x;
  const int i = blockIdx.x;
  const int l = t & 63;
  const int wv = t >> 6;
  const int strip = wv * 32;
  const int l15 = l & 15;
  const int lg = l >> 4;
  const int hiSel = (l >> 5) & 1;
  const int aLo = ((((lg & 1) * 2 + 0) * 16) + l15) * 4;
  const int aHi = ((((lg & 1) * 2 + 1) * 16) + l15) * 4;

  // ---- Phase A: X[i,j,:] = x0[j] + a0[i] (own strip rows) ----
  {
    const int j = t >> 1, hf = t & 1;
    const float* xr = p.x0 + j * 128 + hf * 64;
    const float* ar = p.a0 + i * 128 + hf * 64;
#pragma unroll
    for (int c = 0; c < 16; ++c) {
      f32x4 a = *(const f32x4*)(xr + c * 4);
      f32x4 b = *(const f32x4*)(ar + c * 4);
      a += b;
      *(f32x4*)&sX[XF(j, hf * 64 + c * 4)] = a;
    }
  }

  // ---- FFN0 ----
  ffn_phase(sX, sAux, t, strip, l, p.n2a, p.n2b, p.wff, p.b1,
            p.wff + 65536, p.b2, aLo, aHi, hiSel);

  // ---- layer-1 attention ----
  {
    const float* __restrict__ qb1 = p.qb + 128;
    const float* __restrict__ kb1 = p.kb + 128;
    const float* __restrict__ vb1 = p.vb + 128;
    const float* __restrict__ ob1 = p.ob + 128;

    f16x8 x2f[4][2];
#pragma unroll
    for (int nt = 0; nt < 2; ++nt) {
      f16x8 tmp[4];
      build_x2_pass(sX, strip, nt, l, p.n1a + 128, p.n1b + 128, tmp);
#pragma unroll
      for (int kt = 0; kt < 4; ++kt) x2f[kt][nt] = tmp[kt];
    }

#pragma unroll 1
    for (int h = 0; h < 4; ++h) {
      __syncthreads();
      // stage kvq head h (pre-swizzled -> linear copy)
      *(f16x8*)(sAux + t * 8)        = *(const f16x8*)(p.wkvq + h * 4096 + t * 8);
      *(f16x8*)(sAux + 4096 + t * 8) = *(const f16x8*)(p.wkvq + 16384 + h * 4096 + t * 8);
      *(f16x8*)(sAux + 8192 + t * 8) = *(const f16x8*)(p.wkvq + 32768 + h * 4096 + t * 8);
      __syncthreads();

      // ---- gen K, V, Q (A-frags from staged LDS) ----
      f32x4 kacc[2][2], vacc[2][2], qacc[2][2];
#pragma unroll
      for (int mt = 0; mt < 2; ++mt) {
        f32x4 kb4 = *(const f32x4*)&kb1[h * 32 + mt * 16 + lg * 4];
        f32x4 vb4 = *(const f32x4*)&vb1[h * 32 + mt * 16 + lg * 4];
        f32x4 qb4 = *(const f32x4*)&qb1[h * 32 + mt * 16 + lg * 4];
        kacc[mt][0] = kb4; kacc[mt][1] = kb4;
        vacc[mt][0] = vb4; vacc[mt][1] = vb4;
        qacc[mt][0] = qb4; qacc[mt][1] = qb4;
      }
      __builtin_amdgcn_s_setprio(1);
#pragma unroll
      for (int mt = 0; mt < 2; ++mt)
#pragma unroll
        for (int kt = 0; kt < 4; ++kt) {
          const int off = (mt * 16 + l15) * 128 + (((kt * 4 + lg) ^ l15) << 3);
          f16x8 ak = *(const f16x8*)(sAux + off);
          f16x8 av = *(const f16x8*)(sAux + 4096 + off);
          f16x8 aq = *(const f16x8*)(sAux + 8192 + off);
          kacc[mt][0] = MFMA(ak, x2f[kt][0], kacc[mt][0]);
          kacc[mt][1] = MFMA(ak, x2f[kt][1], kacc[mt][1]);
          vacc[mt][0] = MFMA(av, x2f[kt][0], vacc[mt][0]);
          vacc[mt][1] = MFMA(av, x2f[kt][1], vacc[mt][1]);
          qacc[mt][0] = MFMA(aq, x2f[kt][0], qacc[mt][0]);
          qacc[mt][1] = MFMA(aq, x2f[kt][1], qacc[mt][1]);
        }
      __builtin_amdgcn_s_setprio(0);
#pragma unroll
      for (int mt = 0; mt < 2; ++mt)
#pragma unroll
        for (int nt = 0; nt < 2; ++nt)
#pragma unroll
          for (int e = 0; e < 4; ++e) qacc[mt][nt][e] *= INV_SQRT_DK;
      f16x8 qf[2];
      qf[0] = make_bfrag(qacc[0][0], qacc[1][0], aLo, aHi, hiSel);
      qf[1] = make_bfrag(qacc[0][1], qacc[1][1], aLo, aHi, hiSel);
      __syncthreads();   // all waves done reading staged weights

      // ---- write K [256][32] @0, VT [32][256] @8192 (overwrite weights) ----
#pragma unroll
      for (int mt = 0; mt < 2; ++mt)
#pragma unroll
        for (int nt = 0; nt < 2; ++nt) {
          const int j = strip + nt * 16 + l15;
          const int db = mt * 16 + lg * 4;
          uint2 w;
          w.x = pack2(kacc[mt][nt][0], kacc[mt][nt][1]);
          w.y = pack2(kacc[mt][nt][2], kacc[mt][nt][3]);
          *(uint2*)(sAux + j * 32 + (db ^ ((j & 3) << 3))) = w;
#pragma unroll
          for (int e = 0; e < 4; ++e) {
            const int d = mt * 16 + lg * 4 + e;
            sAux[8192 + d * 256 + (j ^ ((d & 7) << 3))] = (_Float16)vacc[mt][nt][e];
          }
        }
      __syncthreads();   // K/VT visible

      // ---- flash over 8 k-tiles, both row-passes ----
#pragma unroll
      for (int nt = 0; nt < 2; ++nt) {
        float mrun = -3e38f, lsum = 0.f;
        f32x4 oacc[2];
        { f32x4 z = {0.f, 0.f, 0.f, 0.f}; oacc[0] = z; oacc[1] = z; }
#pragma unroll 1
        for (int ktile = 0; ktile < 8; ++ktile) {
          f32x4 sacc[2];
#pragma unroll
          for (int mt2 = 0; mt2 < 2; ++mt2) {
            const int k = ktile * 32 + mt2 * 16 + l15;
            f16x8 a = *(const f16x8*)(sAux + k * 32 + ((lg * 8) ^ ((k & 3) << 3)));
            f32x4 z = {0.f, 0.f, 0.f, 0.f};
            sacc[mt2] = MFMA(a, qf[nt], z);
          }
          float tm = -3e38f;
#pragma unroll
          for (int mt2 = 0; mt2 < 2; ++mt2)
#pragma unroll
            for (int e = 0; e < 4; ++e) tm = fmaxf(tm, sacc[mt2][e]);
          tm = fmaxf(tm, __shfl_xor(tm, 16));
          tm = fmaxf(tm, __shfl_xor(tm, 32));
          const float mnew = fmaxf(mrun, tm);
          const float corr = __expf(mrun - mnew);
          float ts = 0.f;
#pragma unroll
          for (int mt2 = 0; mt2 < 2; ++mt2)
#pragma unroll
            for (int e = 0; e < 4; ++e) {
              float ev = __expf(sacc[mt2][e] - mnew);
              sacc[mt2][e] = ev;
              ts += ev;
            }
          ts += __shfl_xor(ts, 16);
          ts += __shfl_xor(ts, 32);
          lsum = fmaf(lsum, corr, ts);
          oacc[0] *= corr; oacc[1] *= corr;
          f16x8 pf = make_bfrag(sacc[0], sacc[1], aLo, aHi, hiSel);
#pragma unroll
          for (int mt2 = 0; mt2 < 2; ++mt2) {
            const int d = mt2 * 16 + l15;
            f16x8 a = *(const f16x8*)(sAux + 8192 + d * 256 + ((ktile * 32 + lg * 8) ^ ((d & 7) << 3)));
            oacc[mt2] = MFMA(a, pf, oacc[mt2]);
          }
          mrun = mnew;
        }
        const float linv = 1.f / lsum;
        oacc[0] *= linv; oacc[1] *= linv;
        f16x8 of = make_bfrag(oacc[0], oacc[1], aLo, aHi, hiSel);
        // Z = ow_h @ O^T (ow linear from L2) + residual into sX
        f32x4 zacc[8];
#pragma unroll
        for (int mt = 0; mt < 8; ++mt) {
          if (h == 0) zacc[mt] = *(const f32x4*)&ob1[mt * 16 + lg * 4];
          else { f32x4 z = {0.f, 0.f, 0.f, 0.f}; zacc[mt] = z; }
        }
        __builtin_amdgcn_s_setprio(1);
#pragma unroll
        for (int mt = 0; mt < 8; ++mt) {
          f16x8 a = *(const f16x8*)(p.wow + (mt * 16 + l15) * 128 + h * 32 + lg * 8);
          zacc[mt] = MFMA(a, of, zacc[mt]);
        }
        __builtin_amdgcn_s_setprio(0);
        const int row = strip + nt * 16 + l15;
#pragma unroll
        for (int mt = 0; mt < 8; ++mt) {
          float* dst = &sX[XF(row, mt * 16 + lg * 4)];
          f32x4 v = *(const f32x4*)dst;
          v += zacc[mt];
          *(f32x4*)dst = v;
        }
      }
      // next h's top barrier protects aux
    }
  }

  // ---- FFN1 ----
  ffn_phase(sX, sAux, t, strip, l, p.n2a + 128, p.n2b + 128,
            p.wff + 131072, p.b1 + 512, p.wff + 196608, p.b2 + 128,
            aLo, aHi, hiSel);

  // ---- final norm + output projection ----
  {
    const int r = strip + (l & 31), hf = l >> 5;
    float sum = 0.f, sq = 0.f;
#pragma unroll
    for (int c = 0; c < 16; ++c) {
      f32x4 v = *(const f32x4*)&sX[XF(r, hf * 64 + c * 4)];
#pragma unroll
      for (int e = 0; e < 4; ++e) { sum += v[e]; sq = fmaf(v[e], v[e], sq); }
    }
    sum += __shfl_xor(sum, 32);
    sq  += __shfl_xor(sq, 32);
    float mu = sum * (1.f / 128.f);
    float var = fmaf(-sum, mu, sq) * (1.f / 127.f);
    float inv = 1.f / (sqrtf(var) + 1e-6f);
    float os = 0.f;
#pragma unroll
    for (int c = 0; c < 16; ++c) {
      f32x4 x  = *(const f32x4*)&sX[XF(r, hf * 64 + c * 4)];
      f32x4 fa = *(const f32x4*)&p.fna[hf * 64 + c * 4];
      f32x4 fb = *(const f32x4*)&p.fnb[hf * 64 + c * 4];
      f32x4 wo = *(const f32x4*)&p.out_w[hf * 64 + c * 4];
#pragma unroll
      for (int e = 0; e < 4; ++e)
        os = fmaf(fmaf(fa[e] * inv, x[e] - mu, fb[e]), wo[e], os);
    }
    os += __shfl_xor(os, 32);
    if (l < 32) p.out[i * 256 + r] = os + p.out_b[0];
  }
}

// ---------------- host ----------------
extern "C" void kernel_launch(void* const* d_in, const int* in_sizes, int n_in,
                              void* d_out, int out_size, void* d_ws, size_t ws_size,
                              hipStream_t stream) {
  float* x0 = (float*)d_ws;                           // 32768 f32
  float* a0 = x0 + 32768;                             // 32768 f32
  _Float16* W16 = (_Float16*)((char*)d_ws + 262144);  // 327680 halves

  P0 p0;
  p0.qw = (const float*)d_in[8];  p0.kw = (const float*)d_in[10];
  p0.vw = (const float*)d_in[12]; p0.ow = (const float*)d_in[14];
  p0.w1 = (const float*)d_in[20]; p0.w2 = (const float*)d_in[22];
  p0.dst = W16;
  convswz<<<dim3(1280), dim3(256), 0, stream>>>(p0);

  P1 p1;
  p1.src  = (const float*)d_in[0];
  p1.t    = (const int*)  d_in[1];
  p1.fc_w = (const float*)d_in[2];  p1.fc_b = (const float*)d_in[3];
  p1.gc_w = (const float*)d_in[4];  p1.gc_b = (const float*)d_in[5];
  p1.ln_w = (const float*)d_in[6];  p1.ln_b = (const float*)d_in[7];
  p1.n1a  = (const float*)d_in[16]; p1.n1b  = (const float*)d_in[17];
  p1.vw   = (const float*)d_in[12]; p1.vb   = (const float*)d_in[13];
  p1.ow   = (const float*)d_in[14]; p1.ob   = (const float*)d_in[15];
  p1.x0 = x0; p1.a0 = a0;
  prep<<<dim3(128), dim3(256), 0, stream>>>(p1);

  P2 p2;
  p2.x0 = x0; p2.a0 = a0;
  p2.wff  = W16;
  p2.wkvq = W16 + 262144;
  p2.wow  = W16 + 311296;
  p2.qb = (const float*)d_in[9];  p2.kb = (const float*)d_in[11];
  p2.vb = (const float*)d_in[13]; p2.ob = (const float*)d_in[15];
  p2.n1a = (const float*)d_in[16]; p2.n1b = (const float*)d_in[17];
  p2.n2a = (const float*)d_in[18]; p2.n2b = (const float*)d_in[19];
  p2.b1 = (const float*)d_in[21];  p2.b2 = (const float*)d_in[23];
  p2.fna = (const float*)d_in[24]; p2.fnb = (const float*)d_in[25];
  p2.out_w = (const float*)d_in[26]; p2.out_b = (const float*)d_in[27];
  p2.out = (float*)d_out;
  batchk<<<dim3(256), dim3(512), 0, stream>>>(p2);
}

// Round 13
// 138.481 us; speedup vs baseline: 1.1771x; 1.1771x over previous
//
#include <hip/hip_runtime.h>
#include <math.h>

// r13 BISECTION: 32x32 FFN (r12's fixed t1frag path) + VERBATIM r8 attention
// (16x16, proven 142us). If PASS: t1frag + 32x32 A/B layout verified, r12 bug
// is in attention stores/flash. If FAIL: 32x32 mapping convicted -> revert r8.

#define SQRT_D 11.313708498984761f
#define PE_C   0.14391156831212787f
#define INV_SQRT_DK 0.17677669529663687f
#define XF(j,d) (((j) << 7) + ((d) ^ (((j) & 15) << 2)))

typedef _Float16 f16x8 __attribute__((ext_vector_type(8)));
typedef float    f32x4 __attribute__((ext_vector_type(4)));
typedef float    f32x16 __attribute__((ext_vector_type(16)));

#define MFMA16(a, b, c) __builtin_amdgcn_mfma_f32_16x16x32_f16((a), (b), (c), 0, 0, 0)
#define MFMA32(a, b, c) __builtin_amdgcn_mfma_f32_32x32x16_f16((a), (b), (c), 0, 0, 0)

__device__ __forceinline__ unsigned pack2(float a, float b) {
  union { _Float16 h; unsigned short s; } ua, ub;
  ua.h = (_Float16)a; ub.h = (_Float16)b;
  return (unsigned)ua.s | ((unsigned)ub.s << 16);
}

__device__ __forceinline__ f16x8 u4f16x8(unsigned u0, unsigned u1, unsigned u2, unsigned u3) {
  union { unsigned u[4]; f16x8 f; } x;
  x.u[0] = u0; x.u[1] = u1; x.u[2] = u2; x.u[3] = u3;
  return x.f;
}

// ---- 16x16 infra (r8 verbatim) ----
__device__ __forceinline__ unsigned bperm(int addr, unsigned v) {
  return (unsigned)__builtin_amdgcn_ds_bpermute(addr, (int)v);
}

__device__ __forceinline__ f16x8 make_bfrag(f32x4 cA, f32x4 cB, int aLo, int aHi, int hiSel) {
  unsigned a0 = pack2(cA[0], cA[1]), a1 = pack2(cA[2], cA[3]);
  unsigned b0 = pack2(cB[0], cB[1]), b1 = pack2(cB[2], cB[3]);
  unsigned lA0 = bperm(aLo, a0), lA1 = bperm(aLo, a1);
  unsigned hA0 = bperm(aHi, a0), hA1 = bperm(aHi, a1);
  unsigned lB0 = bperm(aLo, b0), lB1 = bperm(aLo, b1);
  unsigned hB0 = bperm(aHi, b0), hB1 = bperm(aHi, b1);
  return u4f16x8(hiSel ? lB0 : lA0, hiSel ? lB1 : lA1,
                 hiSel ? hB0 : hA0, hiSel ? hB1 : hA1);
}

// ---- 32x32 infra (r12, fixed) ----
__device__ __forceinline__ void swapP(unsigned& x, unsigned& y) {
  asm("v_permlane32_swap_b32 %0, %1" : "+v"(x), "+v"(y));
}

__device__ __forceinline__ float crossHalf(float v, int h) {
  unsigned a = __float_as_uint(v), b = a;
  swapP(a, b);            // a = lo-replicated, b = hi-replicated
  return __uint_as_float(h ? a : b);
}

__device__ __forceinline__ f16x8 t1frag(const f32x16& c, int kt) {
  const int b = kt * 8;
  unsigned p0 = pack2(c[b + 0], c[b + 1]);
  unsigned p1 = pack2(c[b + 2], c[b + 3]);
  unsigned q0 = pack2(c[b + 4], c[b + 5]);
  unsigned q1 = pack2(c[b + 6], c[b + 7]);
  swapP(p0, q0);   // p0=[P0.lo|Q0.lo] (word0), q0=[P0.hi|Q0.hi] (word2)
  swapP(p1, q1);
  return u4f16x8(p0, p1, q0, q1);
}

__device__ __forceinline__ f32x16 zero16() {
  f32x16 z;
#pragma unroll
  for (int e = 0; e < 16; ++e) z[e] = 0.f;
  return z;
}

__device__ __forceinline__ f32x16 bias16(const float* __restrict__ b, int base, int h) {
  f32x16 c;
#pragma unroll
  for (int q = 0; q < 4; ++q) {
    f32x4 v = *(const f32x4*)&b[base + q * 8 + 4 * h];
#pragma unroll
    for (int e = 0; e < 4; ++e) c[q * 4 + e] = v[e];
  }
  return c;
}

__device__ __forceinline__ void flush16(float* sX, int row, int D0, int h, const f32x16& c) {
#pragma unroll
  for (int q = 0; q < 4; ++q) {
    float* dst = &sX[XF(row, D0 + q * 8 + 4 * h)];
    f32x4 v = *(const f32x4*)dst;
#pragma unroll
    for (int e = 0; e < 4; ++e) v[e] += c[q * 4 + e];
    *(f32x4*)dst = v;
  }
}

// ---------------- K0: f32 -> f16; FFN blocked, kvq/ow linear ----------------
// W16: [0:64K) w1L0 blk | [64K:128K) w2L0 blk | [128K:192K) w1L1 | [192K:256K)
// w2L1 | [256K:272K) kwL1 lin | [272K:288K) vwL1 | [288K:304K) qwL1 | ow lin.
struct P0 { const float *qw, *kw, *vw, *ow, *w1, *w2; _Float16* dst; };

__global__ __launch_bounds__(256) void convblk(P0 p) {
  const int i = blockIdx.x * 256 + threadIdx.x;   // 1280 blocks -> 327680
  const float* src; int sidx;
  if (i < 262144) {
    const int L = i >> 17;
    const int r = i & 131071;
    if (r < 65536) {          // w1 blocked [c8][ut2][g16][r32][e8]
      const int c = r >> 13, rem = r & 8191;
      const int ut = rem >> 12, g = (rem >> 8) & 15, row = (rem >> 3) & 31, e = rem & 7;
      sidx = L * 65536 + (c * 64 + ut * 32 + row) * 128 + g * 8 + e;
      src = p.w1;
    } else {                  // w2 blocked [c8][dt4][g8][r32][e8]
      const int r2 = r - 65536;
      const int c = r2 >> 13, rem = r2 & 8191;
      const int dt = rem >> 11, g = (rem >> 8) & 7, row = (rem >> 3) & 31, e = rem & 7;
      sidx = L * 65536 + (dt * 32 + row) * 512 + c * 64 + g * 8 + e;
      src = p.w2;
    }
  } else {                    // kvq+ow layer-1, linear row-major
    const int j = i - 262144;
    const int m = j >> 14;    // 0=k 1=v 2=q 3=ow
    sidx = 16384 + (j & 16383);
    src = (m == 0) ? p.kw : (m == 1 ? p.vw : (m == 2 ? p.qw : p.ow));
  }
  p.dst[i] = (_Float16)src[sidx];
}

// ---------------- K1: prep (verified r3) ----------------
struct P1 {
  const float* src; const int* t;
  const float* fc_w; const float* fc_b; const float* gc_w; const float* gc_b;
  const float* ln_w; const float* ln_b;
  const float* n1a; const float* n1b;
  const float* vw; const float* vb; const float* ow; const float* ob;
  float* x0; float* a0;
};

__device__ __forceinline__ float rowReduceSum(float v, volatile float* red, int d) {
#pragma unroll
  for (int off = 32; off > 0; off >>= 1) v += __shfl_xor(v, off, 64);
  if ((d & 63) == 0) red[d >> 6] = v;
  __syncthreads();
  float r = red[0] + red[1];
  __syncthreads();
  return r;
}

__device__ __forceinline__ float dot128s(const float* __restrict__ w,
                                         const float* __restrict__ xs) {
  const float4* __restrict__ w4 = (const float4*)w;
  const float4* __restrict__ x4 = (const float4*)xs;
  float a0 = 0.f, a1 = 0.f, a2 = 0.f, a3 = 0.f;
#pragma unroll
  for (int k = 0; k < 32; k += 4) {
    float4 xv0 = x4[k + 0], xv1 = x4[k + 1], xv2 = x4[k + 2], xv3 = x4[k + 3];
    float4 wv0 = w4[k + 0], wv1 = w4[k + 1], wv2 = w4[k + 2], wv3 = w4[k + 3];
    a0 = fmaf(wv0.w, xv0.w, fmaf(wv0.z, xv0.z, fmaf(wv0.y, xv0.y, fmaf(wv0.x, xv0.x, a0))));
    a1 = fmaf(wv1.w, xv1.w, fmaf(wv1.z, xv1.z, fmaf(wv1.y, xv1.y, fmaf(wv1.x, xv1.x, a1))));
    a2 = fmaf(wv2.w, xv2.w, fmaf(wv2.z, xv2.z, fmaf(wv2.y, xv2.y, fmaf(wv2.x, xv2.x, a2))));
    a3 = fmaf(wv3.w, xv3.w, fmaf(wv3.z, xv3.z, fmaf(wv3.y, xv3.y, fmaf(wv3.x, xv3.x, a3))));
  }
  return (a0 + a1) + (a2 + a3);
}

__global__ __launch_bounds__(256) void prep(P1 p) {
  __shared__ __align__(16) float s_src[2][16];
  __shared__ __align__(16) float s_x2[2][128];
  __shared__ __align__(16) float s_y[2][128];
  __shared__ float s_red[2][2];

  const int tid = threadIdx.x;
  const int rl  = tid >> 7;
  const int d   = tid & 127;
  const int row = blockIdx.x * 2 + rl;
  volatile float* red = s_red[rl];

  if (d < 14) s_src[rl][d + 1] = p.src[row * 14 + d];
  if (d == 14) { s_src[rl][0] = 0.f; s_src[rl][15] = 0.f; }
  __syncthreads();

  const float fw0 = p.fc_w[3*d+0], fw1 = p.fc_w[3*d+1], fw2 = p.fc_w[3*d+2];
  const float gw0 = p.gc_w[3*d+0], gw1 = p.gc_w[3*d+1], gw2 = p.gc_w[3*d+2];
  const float fb = p.fc_b[d], gb = p.gc_b[d];
  float g = 0.f;
#pragma unroll
  for (int m = 0; m < 14; ++m) {
    float xm1 = s_src[rl][m], x0v = s_src[rl][m+1], xp1 = s_src[rl][m+2];
    float f  = fmaf(fw2, xp1, fmaf(fw1, x0v, fmaf(fw0, xm1, fb)));
    float ga = fmaf(gw2, xp1, fmaf(gw1, x0v, fmaf(gw0, xm1, gb)));
    g = fmaf(f, 1.f / (1.f + expf(-ga)), g);
  }
  g *= (1.f / 14.f);

  float mu = rowReduceSum(g, red, d) * (1.f / 128.f);
  float cg = g - mu;
  float var = rowReduceSum(cg * cg, red, d) * (1.f / 128.f);
  float x = fmaf(p.ln_w[d], cg * rsqrtf(var + 1e-5f), p.ln_b[d]);

  const int tval = *p.t;
  {
    int i2 = d >> 1;
    float arg = (float)tval * expf((float)i2 * -PE_C);
    float pe = (d & 1) ? cosf(arg) : sinf(arg);
    x = fmaf(x, SQRT_D, pe);
  }
  p.x0[row * 128 + d] = x;

  float mu1 = rowReduceSum(x, red, d) * (1.f / 128.f);
  float c1 = x - mu1;
  float v1 = rowReduceSum(c1 * c1, red, d) * (1.f / 127.f);
  s_x2[rl][d] = fmaf(p.n1a[d], c1 / (sqrtf(v1) + 1e-6f), p.n1b[d]);
  __syncthreads();

  float y = p.vb[d] + dot128s(p.vw + d * 128, s_x2[rl]);
  s_y[rl][d] = y;
  __syncthreads();
  p.a0[row * 128 + d] = p.ob[d] + dot128s(p.ow + d * 128, s_y[rl]);
}

// ---------------- K2 ----------------
struct P2 {
  const float* x0; const float* a0;
  const _Float16* wff;                     // blocked FFN (262144 f16)
  const _Float16 *wk16, *wv16, *wq16, *wow; // linear layer-1 (16384 f16 each)
  const float *qb, *kb, *vb, *ob;
  const float *n1a, *n1b, *n2a, *n2b;
  const float *b1, *b2;
  const float *fna, *fnb, *out_w, *out_b;
  float* out;
};

// r8 16-row norm -> B-frags out[4] (verbatim)
__device__ __forceinline__ void build_x2_pass(const float* sX, int strip, int nt, int l,
    const float* __restrict__ na, const float* __restrict__ nb, f16x8 out[4]) {
  const int l15 = l & 15, q = l >> 4;
  const int row = strip + nt * 16 + l15;
  float sum = 0.f, sq = 0.f;
#pragma unroll
  for (int c4 = 0; c4 < 8; ++c4) {
    f32x4 v = *(const f32x4*)&sX[XF(row, q * 32 + c4 * 4)];
#pragma unroll
    for (int e = 0; e < 4; ++e) { sum += v[e]; sq = fmaf(v[e], v[e], sq); }
  }
  sum += __shfl_xor(sum, 16); sum += __shfl_xor(sum, 32);
  sq  += __shfl_xor(sq, 16);  sq  += __shfl_xor(sq, 32);
  const float mu = sum * (1.f / 128.f);
  const float var = fmaf(-sum, mu, sq) * (1.f / 127.f);
  const float inv = 1.f / (sqrtf(var) + 1e-6f);
#pragma unroll
  for (int kt = 0; kt < 4; ++kt) {
    const int d0 = kt * 32 + q * 8;
    f32x4 xA = *(const f32x4*)&sX[XF(row, d0)];
    f32x4 xB = *(const f32x4*)&sX[XF(row, d0 + 4)];
    f32x4 nA = *(const f32x4*)&na[d0], nB = *(const f32x4*)&na[d0 + 4];
    f32x4 bA = *(const f32x4*)&nb[d0], bB = *(const f32x4*)&nb[d0 + 4];
    float v0 = fmaf(nA[0] * inv, xA[0] - mu, bA[0]);
    float v1 = fmaf(nA[1] * inv, xA[1] - mu, bA[1]);
    float v2 = fmaf(nA[2] * inv, xA[2] - mu, bA[2]);
    float v3 = fmaf(nA[3] * inv, xA[3] - mu, bA[3]);
    float v4 = fmaf(nB[0] * inv, xB[0] - mu, bB[0]);
    float v5 = fmaf(nB[1] * inv, xB[1] - mu, bB[1]);
    float v6 = fmaf(nB[2] * inv, xB[2] - mu, bB[2]);
    float v7 = fmaf(nB[3] * inv, xB[3] - mu, bB[3]);
    out[kt] = u4f16x8(pack2(v0, v1), pack2(v2, v3), pack2(v4, v5), pack2(v6, v7));
  }
}

// r12 32-row norm -> 8 B-frags (k-slices of 16)
__device__ __forceinline__ void build_x2(const float* sX, int strip, int l,
    const float* __restrict__ na, const float* __restrict__ nb, f16x8 out[8]) {
  const int h = l >> 5, row = strip + (l & 31);
  f32x4 xs[16];
  float sum = 0.f, sq = 0.f;
#pragma unroll
  for (int s = 0; s < 8; ++s) {
    f32x4 a = *(const f32x4*)&sX[XF(row, s * 16 + 8 * h)];
    f32x4 b = *(const f32x4*)&sX[XF(row, s * 16 + 8 * h + 4)];
    xs[2 * s] = a; xs[2 * s + 1] = b;
#pragma unroll
    for (int e = 0; e < 4; ++e) {
      sum += a[e] + b[e];
      sq = fmaf(a[e], a[e], fmaf(b[e], b[e], sq));
    }
  }
  sum += crossHalf(sum, h);
  sq  += crossHalf(sq, h);
  const float mu = sum * (1.f / 128.f);
  const float var = fmaf(-sum, mu, sq) * (1.f / 127.f);
  const float inv = 1.f / (sqrtf(var) + 1e-6f);
#pragma unroll
  for (int s = 0; s < 8; ++s) {
    const int d0 = s * 16 + 8 * h;
    f32x4 nA = *(const f32x4*)&na[d0], nB = *(const f32x4*)&na[d0 + 4];
    f32x4 bA = *(const f32x4*)&nb[d0], bB = *(const f32x4*)&nb[d0 + 4];
    float v[8];
#pragma unroll
    for (int e = 0; e < 4; ++e) {
      v[e]     = fmaf(nA[e] * inv, xs[2 * s][e] - mu, bA[e]);
      v[4 + e] = fmaf(nB[e] * inv, xs[2 * s + 1][e] - mu, bB[e]);
    }
    out[s] = u4f16x8(pack2(v[0], v[1]), pack2(v[2], v[3]),
                     pack2(v[4], v[5]), pack2(v[6], v[7]));
  }
}

// r12 32x32 FFN (fixed t1frag). aux/chunk: w1c blk [0:8192), w2c blk [8192:16384).
__device__ __forceinline__ void ffn_phase(float* sX, _Float16* aux, int t,
    int strip, int l, const float* __restrict__ na, const float* __restrict__ nb,
    const _Float16* __restrict__ w1blk, const float* __restrict__ b1,
    const _Float16* __restrict__ w2blk, const float* __restrict__ b2) {
  const int h = l >> 5, row = strip + (l & 31);
  f16x8 x2f[8];
  build_x2(sX, strip, l, na, nb, x2f);
#pragma unroll 1
  for (int c = 0; c < 8; ++c) {
    __syncthreads();
    {
      const _Float16* w1c = w1blk + c * 8192;
      const _Float16* w2c = w2blk + c * 8192;
      *(f16x8*)(aux + t * 8)         = *(const f16x8*)(w1c + t * 8);
      *(f16x8*)(aux + 4096 + t * 8)  = *(const f16x8*)(w1c + 4096 + t * 8);
      *(f16x8*)(aux + 8192 + t * 8)  = *(const f16x8*)(w2c + t * 8);
      *(f16x8*)(aux + 12288 + t * 8) = *(const f16x8*)(w2c + 4096 + t * 8);
    }
    __syncthreads();
    f32x16 hacc[2];
#pragma unroll
    for (int ut = 0; ut < 2; ++ut) {
      hacc[ut] = bias16(b1, c * 64 + ut * 32, h);
#pragma unroll
      for (int s = 0; s < 8; ++s) {
        f16x8 a = *(const f16x8*)(aux + ut * 4096 + s * 512 + l * 8);
        hacc[ut] = MFMA32(a, x2f[s], hacc[ut]);
      }
#pragma unroll
      for (int e = 0; e < 16; ++e) hacc[ut][e] = fmaxf(hacc[ut][e], 0.f);
    }
    f16x8 hf[4];
#pragma unroll
    for (int ks = 0; ks < 4; ++ks) hf[ks] = t1frag(hacc[ks >> 1], ks & 1);
#pragma unroll 1
    for (int dt = 0; dt < 4; ++dt) {
      f32x16 oacc = (c == 0) ? bias16(b2, dt * 32, h) : zero16();
#pragma unroll
      for (int ks = 0; ks < 4; ++ks) {
        f16x8 a = *(const f16x8*)(aux + 8192 + dt * 2048 + ks * 512 + l * 8);
        oacc = MFMA32(a, hf[ks], oacc);
      }
      flush16(sX, row, dt * 32, h, oacc);
    }
  }
}

__global__ __launch_bounds__(512) void batchk(P2 p) {
  __shared__ __align__(16) float sX[32768];        // 128 KB, XF-swizzled
  __shared__ __align__(16) _Float16 sAux[16384];   // 32 KB

  const int t = threadIdx.x;
  const int i = blockIdx.x;
  const int l = t & 63;
  const int wv = t >> 6;
  const int strip = wv * 32;
  const int l15 = l & 15;
  const int lg = l >> 4;
  const int hiSel = (l >> 5) & 1;
  const int aLo = ((((lg & 1) * 2 + 0) * 16) + l15) * 4;
  const int aHi = ((((lg & 1) * 2 + 1) * 16) + l15) * 4;

  // ---- Phase A (r8 verbatim) ----
  {
    const int j = t >> 1, hf = t & 1;
    const float* xr = p.x0 + j * 128 + hf * 64;
    const float* ar = p.a0 + i * 128 + hf * 64;
#pragma unroll
    for (int c = 0; c < 16; ++c) {
      f32x4 a = *(const f32x4*)(xr + c * 4);
      f32x4 b = *(const f32x4*)(ar + c * 4);
      a += b;
      *(f32x4*)&sX[XF(j, hf * 64 + c * 4)] = a;
    }
  }

  // ---- FFN0 (32x32 path) ----
  ffn_phase(sX, sAux, t, strip, l, p.n2a, p.n2b, p.wff, p.b1,
            p.wff + 65536, p.b2);

  // ---- layer-1 attention (r8 VERBATIM, 16x16) ----
  {
    const float* __restrict__ qb1 = p.qb + 128;
    const float* __restrict__ kb1 = p.kb + 128;
    const float* __restrict__ vb1 = p.vb + 128;
    const float* __restrict__ ob1 = p.ob + 128;

    f16x8 x2f[4][2];
#pragma unroll
    for (int nt = 0; nt < 2; ++nt) {
      f16x8 tmp[4];
      build_x2_pass(sX, strip, nt, l, p.n1a + 128, p.n1b + 128, tmp);
#pragma unroll
      for (int kt = 0; kt < 4; ++kt) x2f[kt][nt] = tmp[kt];
    }

    const int sr = t >> 4, sg = t & 15;

#pragma unroll 1
    for (int h = 0; h < 4; ++h) {
      __syncthreads();
      {
        f16x8 v0 = *(const f16x8*)(p.wk16 + (h * 32 + sr) * 128 + sg * 8);
        *(f16x8*)(sAux + sr * 128 + ((sg ^ (sr & 15)) << 3)) = v0;
        f16x8 v1 = *(const f16x8*)(p.wv16 + (h * 32 + sr) * 128 + sg * 8);
        *(f16x8*)(sAux + 4096 + sr * 128 + ((sg ^ (sr & 15)) << 3)) = v1;
        f16x8 v2 = *(const f16x8*)(p.wq16 + (h * 32 + sr) * 128 + sg * 8);
        *(f16x8*)(sAux + 8192 + sr * 128 + ((sg ^ (sr & 15)) << 3)) = v2;
      }
      __syncthreads();

      f32x4 kacc[2][2], vacc[2][2], qacc[2][2];
#pragma unroll
      for (int mt = 0; mt < 2; ++mt) {
        f32x4 kb4 = *(const f32x4*)&kb1[h * 32 + mt * 16 + lg * 4];
        f32x4 vb4 = *(const f32x4*)&vb1[h * 32 + mt * 16 + lg * 4];
        f32x4 qb4 = *(const f32x4*)&qb1[h * 32 + mt * 16 + lg * 4];
        kacc[mt][0] = kb4; kacc[mt][1] = kb4;
        vacc[mt][0] = vb4; vacc[mt][1] = vb4;
        qacc[mt][0] = qb4; qacc[mt][1] = qb4;
      }
#pragma unroll
      for (int mt = 0; mt < 2; ++mt)
#pragma unroll
        for (int kt = 0; kt < 4; ++kt) {
          const int off = (mt * 16 + l15) * 128 + (((kt * 4 + lg) ^ l15) << 3);
          f16x8 ak = *(const f16x8*)(sAux + off);
          f16x8 av = *(const f16x8*)(sAux + 4096 + off);
          f16x8 aq = *(const f16x8*)(sAux + 8192 + off);
          kacc[mt][0] = MFMA16(ak, x2f[kt][0], kacc[mt][0]);
          kacc[mt][1] = MFMA16(ak, x2f[kt][1], kacc[mt][1]);
          vacc[mt][0] = MFMA16(av, x2f[kt][0], vacc[mt][0]);
          vacc[mt][1] = MFMA16(av, x2f[kt][1], vacc[mt][1]);
          qacc[mt][0] = MFMA16(aq, x2f[kt][0], qacc[mt][0]);
          qacc[mt][1] = MFMA16(aq, x2f[kt][1], qacc[mt][1]);
        }
#pragma unroll
      for (int mt = 0; mt < 2; ++mt)
#pragma unroll
        for (int nt = 0; nt < 2; ++nt)
#pragma unroll
          for (int e = 0; e < 4; ++e) qacc[mt][nt][e] *= INV_SQRT_DK;
      f16x8 qf[2];
      qf[0] = make_bfrag(qacc[0][0], qacc[1][0], aLo, aHi, hiSel);
      qf[1] = make_bfrag(qacc[0][1], qacc[1][1], aLo, aHi, hiSel);
      __syncthreads();

#pragma unroll
      for (int mt = 0; mt < 2; ++mt)
#pragma unroll
        for (int nt = 0; nt < 2; ++nt) {
          const int j = strip + nt * 16 + l15;
          const int db = mt * 16 + lg * 4;
          uint2 w;
          w.x = pack2(kacc[mt][nt][0], kacc[mt][nt][1]);
          w.y = pack2(kacc[mt][nt][2], kacc[mt][nt][3]);
          *(uint2*)(sAux + j * 32 + (db ^ ((j & 3) << 3))) = w;
#pragma unroll
          for (int e = 0; e < 4; ++e) {
            const int d = mt * 16 + lg * 4 + e;
            sAux[8192 + d * 256 + (j ^ ((d & 7) << 3))] = (_Float16)vacc[mt][nt][e];
          }
        }
      __syncthreads();

#pragma unroll
      for (int nt = 0; nt < 2; ++nt) {
        float mrun = -3e38f, lsum = 0.f;
        f32x4 oacc[2];
        { f32x4 z = {0.f, 0.f, 0.f, 0.f}; oacc[0] = z; oacc[1] = z; }
#pragma unroll 1
        for (int ktile = 0; ktile < 8; ++ktile) {
          f32x4 sacc[2];
#pragma unroll
          for (int mt2 = 0; mt2 < 2; ++mt2) {
            const int k = ktile * 32 + mt2 * 16 + l15;
            f16x8 a = *(const f16x8*)(sAux + k * 32 + ((lg * 8) ^ ((k & 3) << 3)));
            f32x4 z = {0.f, 0.f, 0.f, 0.f};
            sacc[mt2] = MFMA16(a, qf[nt], z);
          }
          float tm = -3e38f;
#pragma unroll
          for (int mt2 = 0; mt2 < 2; ++mt2)
#pragma unroll
            for (int e = 0; e < 4; ++e) tm = fmaxf(tm, sacc[mt2][e]);
          tm = fmaxf(tm, __shfl_xor(tm, 16));
          tm = fmaxf(tm, __shfl_xor(tm, 32));
          const float mnew = fmaxf(mrun, tm);
          const float corr = __expf(mrun - mnew);
          float ts = 0.f;
#pragma unroll
          for (int mt2 = 0; mt2 < 2; ++mt2)
#pragma unroll
            for (int e = 0; e < 4; ++e) {
              float ev = __expf(sacc[mt2][e] - mnew);
              sacc[mt2][e] = ev;
              ts += ev;
            }
          ts += __shfl_xor(ts, 16);
          ts += __shfl_xor(ts, 32);
          lsum = fmaf(lsum, corr, ts);
          oacc[0] *= corr; oacc[1] *= corr;
          f16x8 pf = make_bfrag(sacc[0], sacc[1], aLo, aHi, hiSel);
#pragma unroll
          for (int mt2 = 0; mt2 < 2; ++mt2) {
            const int d = mt2 * 16 + l15;
            f16x8 a = *(const f16x8*)(sAux + 8192 + d * 256 + ((ktile * 32 + lg * 8) ^ ((d & 7) << 3)));
            oacc[mt2] = MFMA16(a, pf, oacc[mt2]);
          }
          mrun = mnew;
        }
        const float linv = 1.f / lsum;
        oacc[0] *= linv; oacc[1] *= linv;
        f16x8 of = make_bfrag(oacc[0], oacc[1], aLo, aHi, hiSel);
        f32x4 zacc[8];
#pragma unroll
        for (int mt = 0; mt < 8; ++mt) {
          if (h == 0) zacc[mt] = *(const f32x4*)&ob1[mt * 16 + lg * 4];
          else { f32x4 z = {0.f, 0.f, 0.f, 0.f}; zacc[mt] = z; }
        }
#pragma unroll
        for (int mt = 0; mt < 8; ++mt) {
          f16x8 a = *(const f16x8*)(p.wow + (mt * 16 + l15) * 128 + h * 32 + lg * 8);
          zacc[mt] = MFMA16(a, of, zacc[mt]);
        }
        const int row = strip + nt * 16 + l15;
#pragma unroll
        for (int mt = 0; mt < 8; ++mt) {
          float* dst = &sX[XF(row, mt * 16 + lg * 4)];
          f32x4 v = *(const f32x4*)dst;
          v += zacc[mt];
          *(f32x4*)dst = v;
        }
      }
    }
  }

  // ---- FFN1 (32x32 path) ----
  ffn_phase(sX, sAux, t, strip, l, p.n2a + 128, p.n2b + 128,
            p.wff + 131072, p.b1 + 512, p.wff + 196608, p.b2 + 128);

  // ---- final norm + output projection (r8 verbatim) ----
  {
    const int r = strip + (l & 31), hf = l >> 5;
    float sum = 0.f, sq = 0.f;
#pragma unroll
    for (int c = 0; c < 16; ++c) {
      f32x4 v = *(const f32x4*)&sX[XF(r, hf * 64 + c * 4)];
#pragma unroll
      for (int e = 0; e < 4; ++e) { sum += v[e]; sq = fmaf(v[e], v[e], sq); }
    }
    sum += __shfl_xor(sum, 32);
    sq  += __shfl_xor(sq, 32);
    float mu = sum * (1.f / 128.f);
    float var = fmaf(-sum, mu, sq) * (1.f / 127.f);
    float inv = 1.f / (sqrtf(var) + 1e-6f);
    float os = 0.f;
#pragma unroll
    for (int c = 0; c < 16; ++c) {
      f32x4 x  = *(const f32x4*)&sX[XF(r, hf * 64 + c * 4)];
      f32x4 fa = *(const f32x4*)&p.fna[hf * 64 + c * 4];
      f32x4 fb = *(const f32x4*)&p.fnb[hf * 64 + c * 4];
      f32x4 wo = *(const f32x4*)&p.out_w[hf * 64 + c * 4];
#pragma unroll
      for (int e = 0; e < 4; ++e)
        os = fmaf(fmaf(fa[e] * inv, x[e] - mu, fb[e]), wo[e], os);
    }
    os += __shfl_xor(os, 32);
    if (l < 32) p.out[i * 256 + r] = os + p.out_b[0];
  }
}

// ---------------- host ----------------
extern "C" void kernel_launch(void* const* d_in, const int* in_sizes, int n_in,
                              void* d_out, int out_size, void* d_ws, size_t ws_size,
                              hipStream_t stream) {
  float* x0 = (float*)d_ws;                           // 32768 f32
  float* a0 = x0 + 32768;                             // 32768 f32
  _Float16* W16 = (_Float16*)((char*)d_ws + 262144);  // 327680 halves

  P0 p0;
  p0.qw = (const float*)d_in[8];  p0.kw = (const float*)d_in[10];
  p0.vw = (const float*)d_in[12]; p0.ow = (const float*)d_in[14];
  p0.w1 = (const float*)d_in[20]; p0.w2 = (const float*)d_in[22];
  p0.dst = W16;
  convblk<<<dim3(1280), dim3(256), 0, stream>>>(p0);

  P1 p1;
  p1.src  = (const float*)d_in[0];
  p1.t    = (const int*)  d_in[1];
  p1.fc_w = (const float*)d_in[2];  p1.fc_b = (const float*)d_in[3];
  p1.gc_w = (const float*)d_in[4];  p1.gc_b = (const float*)d_in[5];
  p1.ln_w = (const float*)d_in[6];  p1.ln_b = (const float*)d_in[7];
  p1.n1a  = (const float*)d_in[16]; p1.n1b  = (const float*)d_in[17];
  p1.vw   = (const float*)d_in[12]; p1.vb   = (const float*)d_in[13];
  p1.ow   = (const float*)d_in[14]; p1.ob   = (const float*)d_in[15];
  p1.x0 = x0; p1.a0 = a0;
  prep<<<dim3(128), dim3(256), 0, stream>>>(p1);

  P2 p2;
  p2.x0 = x0; p2.a0 = a0;
  p2.wff  = W16;
  p2.wk16 = W16 + 262144;
  p2.wv16 = W16 + 278528;
  p2.wq16 = W16 + 294912;
  p2.wow  = W16 + 311296;
  p2.qb = (const float*)d_in[9];  p2.kb = (const float*)d_in[11];
  p2.vb = (const float*)d_in[13]; p2.ob = (const float*)d_in[15];
  p2.n1a = (const float*)d_in[16]; p2.n1b = (const float*)d_in[17];
  p2.n2a = (const float*)d_in[18]; p2.n2b = (const float*)d_in[19];
  p2.b1 = (const float*)d_in[21];  p2.b2 = (const float*)d_in[23];
  p2.fna = (const float*)d_in[24]; p2.fnb = (const float*)d_in[25];
  p2.out_w = (const float*)d_in[26]; p2.out_b = (const float*)d_in[27];
  p2.out = (float*)d_out;
  batchk<<<dim3(256), dim3(512), 0, stream>>>(p2);
}

// Round 14
// 124.132 us; speedup vs baseline: 1.3132x; 1.1156x over previous
//
#include <hip/hip_runtime.h>
#include <math.h>

// r14: full 32x32 megakernel. r13 bisection HW-verified t1frag/crossHalf/
// build_x2/bias16/flush16 and all three 32x32 fragment layouts (via FFN with
// random weights). Attention now 32x32 with:
//  - K exchange via t1frag A-frags written LINEARLY (lane l's frag at
//    wv*1024 + f*512 + l*8; reader lane l reads kt*1024 + f*512 + l*8 and
//    gets exactly its A-frag) -- only HW-verified components, conflict-free.
//  - VT store swizzled-blocked: V[k][dv] -> 8192 + (k>>5)*1024 +
//    ((k&31)>>3)*256 + ((dv^((k&31)>>3))<<3) + (k&7); read a_r = 2f+h.
//  - Z = ow_h @ O^T with ow linear from L2.

#define SQRT_D 11.313708498984761f
#define PE_C   0.14391156831212787f
#define INV_SQRT_DK 0.17677669529663687f
#define XF(j,d) (((j) << 7) + ((d) ^ (((j) & 15) << 2)))

typedef _Float16 f16x8 __attribute__((ext_vector_type(8)));
typedef float    f32x4 __attribute__((ext_vector_type(4)));
typedef float    f32x16 __attribute__((ext_vector_type(16)));

#define MFMA32(a, b, c) __builtin_amdgcn_mfma_f32_32x32x16_f16((a), (b), (c), 0, 0, 0)

__device__ __forceinline__ unsigned pack2(float a, float b) {
  union { _Float16 h; unsigned short s; } ua, ub;
  ua.h = (_Float16)a; ub.h = (_Float16)b;
  return (unsigned)ua.s | ((unsigned)ub.s << 16);
}

__device__ __forceinline__ f16x8 u4f16x8(unsigned u0, unsigned u1, unsigned u2, unsigned u3) {
  union { unsigned u[4]; f16x8 f; } x;
  x.u[0] = u0; x.u[1] = u1; x.u[2] = u2; x.u[3] = u3;
  return x.f;
}

// v_permlane32_swap_b32 vdst, vsrc: after swapP(x,y): x=[x.lo|y.lo], y=[x.hi|y.hi]
__device__ __forceinline__ void swapP(unsigned& x, unsigned& y) {
  asm("v_permlane32_swap_b32 %0, %1" : "+v"(x), "+v"(y));
}

// value of v from the OTHER 32-lane half (same lane&31). HW-verified (r13).
__device__ __forceinline__ float crossHalf(float v, int h) {
  unsigned a = __float_as_uint(v), b = a;
  swapP(a, b);            // a = lo-replicated, b = hi-replicated
  return __uint_as_float(h ? a : b);
}

// C-tile -> frag slice kt (HW-verified r13): lane l elem jj =
// C[m = 16kt + 8*(l>>5) + jj][col = l&31].
__device__ __forceinline__ f16x8 t1frag(const f32x16& c, int kt) {
  const int b = kt * 8;
  unsigned p0 = pack2(c[b + 0], c[b + 1]);
  unsigned p1 = pack2(c[b + 2], c[b + 3]);
  unsigned q0 = pack2(c[b + 4], c[b + 5]);
  unsigned q1 = pack2(c[b + 6], c[b + 7]);
  swapP(p0, q0);
  swapP(p1, q1);
  return u4f16x8(p0, p1, q0, q1);
}

__device__ __forceinline__ f32x16 zero16() {
  f32x16 z;
#pragma unroll
  for (int e = 0; e < 16; ++e) z[e] = 0.f;
  return z;
}

__device__ __forceinline__ f32x16 bias16(const float* __restrict__ b, int base, int h) {
  f32x16 c;
#pragma unroll
  for (int q = 0; q < 4; ++q) {
    f32x4 v = *(const f32x4*)&b[base + q * 8 + 4 * h];
#pragma unroll
    for (int e = 0; e < 4; ++e) c[q * 4 + e] = v[e];
  }
  return c;
}

__device__ __forceinline__ void flush16(float* sX, int row, int D0, int h, const f32x16& c) {
#pragma unroll
  for (int q = 0; q < 4; ++q) {
    float* dst = &sX[XF(row, D0 + q * 8 + 4 * h)];
    f32x4 v = *(const f32x4*)dst;
#pragma unroll
    for (int e = 0; e < 4; ++e) v[e] += c[q * 4 + e];
    *(f32x4*)dst = v;
  }
}

// ---------------- K0: f32 -> f16 + pre-block ----------------
// W16: [0:64K) w1L0 blk | [64K:128K) w2L0 blk | [128K:192K) w1L1 | [192K:256K)
// w2L1 | [256K:304K) kvqL1 blocked [m3][h4][g16][r32][e8] | [304K:320K) owL1 lin.
struct P0 { const float *qw, *kw, *vw, *ow, *w1, *w2; _Float16* dst; };

__global__ __launch_bounds__(256) void convblk(P0 p) {
  const int i = blockIdx.x * 256 + threadIdx.x;   // 1280 blocks -> 327680
  const float* src; int sidx;
  if (i < 262144) {
    const int L = i >> 17;
    const int r = i & 131071;
    if (r < 65536) {          // w1 blocked [c8][ut2][g16][r32][e8]
      const int c = r >> 13, rem = r & 8191;
      const int ut = rem >> 12, g = (rem >> 8) & 15, row = (rem >> 3) & 31, e = rem & 7;
      sidx = L * 65536 + (c * 64 + ut * 32 + row) * 128 + g * 8 + e;
      src = p.w1;
    } else {                  // w2 blocked [c8][dt4][g8][r32][e8]
      const int r2 = r - 65536;
      const int c = r2 >> 13, rem = r2 & 8191;
      const int dt = rem >> 11, g = (rem >> 8) & 7, row = (rem >> 3) & 31, e = rem & 7;
      sidx = L * 65536 + (dt * 32 + row) * 512 + c * 64 + g * 8 + e;
      src = p.w2;
    }
  } else if (i < 311296) {    // kvq layer-1 blocked
    const int j = i - 262144;
    const int m = j >> 14, rem = j & 16383;
    const int hh = rem >> 12, g = (rem >> 8) & 15, row = (rem >> 3) & 31, e = rem & 7;
    sidx = 16384 + (hh * 32 + row) * 128 + g * 8 + e;
    src = (m == 0) ? p.kw : (m == 1 ? p.vw : p.qw);
  } else {                    // ow layer-1 linear
    sidx = 16384 + (i - 311296);
    src = p.ow;
  }
  p.dst[i] = (_Float16)src[sidx];
}

// ---------------- K1: prep (verified r3) ----------------
struct P1 {
  const float* src; const int* t;
  const float* fc_w; const float* fc_b; const float* gc_w; const float* gc_b;
  const float* ln_w; const float* ln_b;
  const float* n1a; const float* n1b;
  const float* vw; const float* vb; const float* ow; const float* ob;
  float* x0; float* a0;
};

__device__ __forceinline__ float rowReduceSum(float v, volatile float* red, int d) {
#pragma unroll
  for (int off = 32; off > 0; off >>= 1) v += __shfl_xor(v, off, 64);
  if ((d & 63) == 0) red[d >> 6] = v;
  __syncthreads();
  float r = red[0] + red[1];
  __syncthreads();
  return r;
}

__device__ __forceinline__ float dot128s(const float* __restrict__ w,
                                         const float* __restrict__ xs) {
  const float4* __restrict__ w4 = (const float4*)w;
  const float4* __restrict__ x4 = (const float4*)xs;
  float a0 = 0.f, a1 = 0.f, a2 = 0.f, a3 = 0.f;
#pragma unroll
  for (int k = 0; k < 32; k += 4) {
    float4 xv0 = x4[k + 0], xv1 = x4[k + 1], xv2 = x4[k + 2], xv3 = x4[k + 3];
    float4 wv0 = w4[k + 0], wv1 = w4[k + 1], wv2 = w4[k + 2], wv3 = w4[k + 3];
    a0 = fmaf(wv0.w, xv0.w, fmaf(wv0.z, xv0.z, fmaf(wv0.y, xv0.y, fmaf(wv0.x, xv0.x, a0))));
    a1 = fmaf(wv1.w, xv1.w, fmaf(wv1.z, xv1.z, fmaf(wv1.y, xv1.y, fmaf(wv1.x, xv1.x, a1))));
    a2 = fmaf(wv2.w, xv2.w, fmaf(wv2.z, xv2.z, fmaf(wv2.y, xv2.y, fmaf(wv2.x, xv2.x, a2))));
    a3 = fmaf(wv3.w, xv3.w, fmaf(wv3.z, xv3.z, fmaf(wv3.y, xv3.y, fmaf(wv3.x, xv3.x, a3))));
  }
  return (a0 + a1) + (a2 + a3);
}

__global__ __launch_bounds__(256) void prep(P1 p) {
  __shared__ __align__(16) float s_src[2][16];
  __shared__ __align__(16) float s_x2[2][128];
  __shared__ __align__(16) float s_y[2][128];
  __shared__ float s_red[2][2];

  const int tid = threadIdx.x;
  const int rl  = tid >> 7;
  const int d   = tid & 127;
  const int row = blockIdx.x * 2 + rl;
  volatile float* red = s_red[rl];

  if (d < 14) s_src[rl][d + 1] = p.src[row * 14 + d];
  if (d == 14) { s_src[rl][0] = 0.f; s_src[rl][15] = 0.f; }
  __syncthreads();

  const float fw0 = p.fc_w[3*d+0], fw1 = p.fc_w[3*d+1], fw2 = p.fc_w[3*d+2];
  const float gw0 = p.gc_w[3*d+0], gw1 = p.gc_w[3*d+1], gw2 = p.gc_w[3*d+2];
  const float fb = p.fc_b[d], gb = p.gc_b[d];
  float g = 0.f;
#pragma unroll
  for (int m = 0; m < 14; ++m) {
    float xm1 = s_src[rl][m], x0v = s_src[rl][m+1], xp1 = s_src[rl][m+2];
    float f  = fmaf(fw2, xp1, fmaf(fw1, x0v, fmaf(fw0, xm1, fb)));
    float ga = fmaf(gw2, xp1, fmaf(gw1, x0v, fmaf(gw0, xm1, gb)));
    g = fmaf(f, 1.f / (1.f + expf(-ga)), g);
  }
  g *= (1.f / 14.f);

  float mu = rowReduceSum(g, red, d) * (1.f / 128.f);
  float cg = g - mu;
  float var = rowReduceSum(cg * cg, red, d) * (1.f / 128.f);
  float x = fmaf(p.ln_w[d], cg * rsqrtf(var + 1e-5f), p.ln_b[d]);

  const int tval = *p.t;
  {
    int i2 = d >> 1;
    float arg = (float)tval * expf((float)i2 * -PE_C);
    float pe = (d & 1) ? cosf(arg) : sinf(arg);
    x = fmaf(x, SQRT_D, pe);
  }
  p.x0[row * 128 + d] = x;

  float mu1 = rowReduceSum(x, red, d) * (1.f / 128.f);
  float c1 = x - mu1;
  float v1 = rowReduceSum(c1 * c1, red, d) * (1.f / 127.f);
  s_x2[rl][d] = fmaf(p.n1a[d], c1 / (sqrtf(v1) + 1e-6f), p.n1b[d]);
  __syncthreads();

  float y = p.vb[d] + dot128s(p.vw + d * 128, s_x2[rl]);
  s_y[rl][d] = y;
  __syncthreads();
  p.a0[row * 128 + d] = p.ob[d] + dot128s(p.ow + d * 128, s_y[rl]);
}

// ---------------- K2: per-batch 32x32 megakernel ----------------
struct P2 {
  const float* x0; const float* a0;
  const _Float16* wff;    // blocked FFN (262144 f16)
  const _Float16* wkvq;   // blocked L1 kvq (49152 f16)
  const _Float16* wow;    // linear L1 ow (16384 f16)
  const float *qb, *kb, *vb, *ob;
  const float *n1a, *n1b, *n2a, *n2b;
  const float *b1, *b2;
  const float *fna, *fnb, *out_w, *out_b;
  float* out;
};

// norm (ddof=1, eps on std) of own row -> 8 B-frags. HW-verified (r13).
__device__ __forceinline__ void build_x2(const float* sX, int strip, int l,
    const float* __restrict__ na, const float* __restrict__ nb, f16x8 out[8]) {
  const int h = l >> 5, row = strip + (l & 31);
  f32x4 xs[16];
  float sum = 0.f, sq = 0.f;
#pragma unroll
  for (int s = 0; s < 8; ++s) {
    f32x4 a = *(const f32x4*)&sX[XF(row, s * 16 + 8 * h)];
    f32x4 b = *(const f32x4*)&sX[XF(row, s * 16 + 8 * h + 4)];
    xs[2 * s] = a; xs[2 * s + 1] = b;
#pragma unroll
    for (int e = 0; e < 4; ++e) {
      sum += a[e] + b[e];
      sq = fmaf(a[e], a[e], fmaf(b[e], b[e], sq));
    }
  }
  sum += crossHalf(sum, h);
  sq  += crossHalf(sq, h);
  const float mu = sum * (1.f / 128.f);
  const float var = fmaf(-sum, mu, sq) * (1.f / 127.f);
  const float inv = 1.f / (sqrtf(var) + 1e-6f);
#pragma unroll
  for (int s = 0; s < 8; ++s) {
    const int d0 = s * 16 + 8 * h;
    f32x4 nA = *(const f32x4*)&na[d0], nB = *(const f32x4*)&na[d0 + 4];
    f32x4 bA = *(const f32x4*)&nb[d0], bB = *(const f32x4*)&nb[d0 + 4];
    float v[8];
#pragma unroll
    for (int e = 0; e < 4; ++e) {
      v[e]     = fmaf(nA[e] * inv, xs[2 * s][e] - mu, bA[e]);
      v[4 + e] = fmaf(nB[e] * inv, xs[2 * s + 1][e] - mu, bB[e]);
    }
    out[s] = u4f16x8(pack2(v[0], v[1]), pack2(v[2], v[3]),
                     pack2(v[4], v[5]), pack2(v[6], v[7]));
  }
}

// 32x32 FFN (HW-verified r13). aux/chunk: w1c blk [0:8192), w2c blk [8192:16384).
__device__ __forceinline__ void ffn_phase(float* sX, _Float16* aux, int t,
    int strip, int l, const float* __restrict__ na, const float* __restrict__ nb,
    const _Float16* __restrict__ w1blk, const float* __restrict__ b1,
    const _Float16* __restrict__ w2blk, const float* __restrict__ b2) {
  const int h = l >> 5, row = strip + (l & 31);
  f16x8 x2f[8];
  build_x2(sX, strip, l, na, nb, x2f);
#pragma unroll 1
  for (int c = 0; c < 8; ++c) {
    __syncthreads();
    {
      const _Float16* w1c = w1blk + c * 8192;
      const _Float16* w2c = w2blk + c * 8192;
      *(f16x8*)(aux + t * 8)         = *(const f16x8*)(w1c + t * 8);
      *(f16x8*)(aux + 4096 + t * 8)  = *(const f16x8*)(w1c + 4096 + t * 8);
      *(f16x8*)(aux + 8192 + t * 8)  = *(const f16x8*)(w2c + t * 8);
      *(f16x8*)(aux + 12288 + t * 8) = *(const f16x8*)(w2c + 4096 + t * 8);
    }
    __syncthreads();
    f32x16 hacc[2];
#pragma unroll
    for (int ut = 0; ut < 2; ++ut) {
      hacc[ut] = bias16(b1, c * 64 + ut * 32, h);
#pragma unroll
      for (int s = 0; s < 8; ++s) {
        f16x8 a = *(const f16x8*)(aux + ut * 4096 + s * 512 + l * 8);
        hacc[ut] = MFMA32(a, x2f[s], hacc[ut]);
      }
#pragma unroll
      for (int e = 0; e < 16; ++e) hacc[ut][e] = fmaxf(hacc[ut][e], 0.f);
    }
    f16x8 hf[4];
#pragma unroll
    for (int ks = 0; ks < 4; ++ks) hf[ks] = t1frag(hacc[ks >> 1], ks & 1);
#pragma unroll 1
    for (int dt = 0; dt < 4; ++dt) {
      f32x16 oacc = (c == 0) ? bias16(b2, dt * 32, h) : zero16();
#pragma unroll
      for (int ks = 0; ks < 4; ++ks) {
        f16x8 a = *(const f16x8*)(aux + 8192 + dt * 2048 + ks * 512 + l * 8);
        oacc = MFMA32(a, hf[ks], oacc);
      }
      flush16(sX, row, dt * 32, h, oacc);
    }
  }
}

__global__ __launch_bounds__(512) void batchk(P2 p) {
  __shared__ __align__(16) float sX[32768];        // 128 KB, XF-swizzled
  __shared__ __align__(16) _Float16 sAux[16384];   // 32 KB

  const int t = threadIdx.x;
  const int i = blockIdx.x;
  const int l = t & 63;
  const int wv = t >> 6;
  const int strip = wv * 32;
  const int h = l >> 5;
  const int row = strip + (l & 31);

  // ---- Phase A: X[i,j,:] = x0[j] + a0[i] ----
  {
    const int j = t >> 1, hf2 = t & 1;
    const float* xr = p.x0 + j * 128 + hf2 * 64;
    const float* ar = p.a0 + i * 128 + hf2 * 64;
#pragma unroll
    for (int c = 0; c < 16; ++c) {
      f32x4 a = *(const f32x4*)(xr + c * 4);
      f32x4 b = *(const f32x4*)(ar + c * 4);
      a += b;
      *(f32x4*)&sX[XF(j, hf2 * 64 + c * 4)] = a;
    }
  }

  // ---- FFN0 ----
  ffn_phase(sX, sAux, t, strip, l, p.n2a, p.n2b, p.wff, p.b1,
            p.wff + 65536, p.b2);

  // ---- layer-1 attention (32x32) ----
  {
    const float* __restrict__ qb1 = p.qb + 128;
    const float* __restrict__ kb1 = p.kb + 128;
    const float* __restrict__ vb1 = p.vb + 128;
    const float* __restrict__ ob1 = p.ob + 128;

    f16x8 x2f[8];
    build_x2(sX, strip, l, p.n1a + 128, p.n1b + 128, x2f);

#pragma unroll 1
    for (int hd = 0; hd < 4; ++hd) {
      __syncthreads();
      // stage kw|vw|qw head hd (blocked -> linear copy): [0:4096) k, [4096:8192) v, [8192:12288) q
#pragma unroll
      for (int r3 = 0; r3 < 3; ++r3)
        *(f16x8*)(sAux + r3 * 4096 + t * 8) =
            *(const f16x8*)(p.wkvq + (r3 * 4 + hd) * 4096 + t * 8);
      __syncthreads();

      // gen K^T / V^T / Q^T C-tiles for own strip
      f32x16 kacc = bias16(kb1, hd * 32, h);
      f32x16 vacc = bias16(vb1, hd * 32, h);
      f32x16 qacc = bias16(qb1, hd * 32, h);
#pragma unroll
      for (int s = 0; s < 8; ++s) {
        f16x8 ak = *(const f16x8*)(sAux + s * 512 + l * 8);
        f16x8 av = *(const f16x8*)(sAux + 4096 + s * 512 + l * 8);
        f16x8 aq = *(const f16x8*)(sAux + 8192 + s * 512 + l * 8);
        kacc = MFMA32(ak, x2f[s], kacc);
        vacc = MFMA32(av, x2f[s], vacc);
        qacc = MFMA32(aq, x2f[s], qacc);
      }
#pragma unroll
      for (int e = 0; e < 16; ++e) qacc[e] *= INV_SQRT_DK;
      f16x8 qf0 = t1frag(qacc, 0), qf1 = t1frag(qacc, 1);
      // K A-frags for own strip via t1frag (HW-verified transform):
      // t1frag(kacc,f) lane l elem jj = K[strip+(l&31)][16f+8h+jj] == the
      // A-frag reader-lane l needs for tile kt=wv, MFMA f.
      f16x8 kf0 = t1frag(kacc, 0), kf1 = t1frag(kacc, 1);
      __syncthreads();   // staged-weight reads complete before overwrite

      // K exchange: linear per-lane frag store (conflict-free 16B/lane)
      *(f16x8*)(sAux + wv * 1024 + l * 8) = kf0;
      *(f16x8*)(sAux + wv * 1024 + 512 + l * 8) = kf1;
      // VT store: V[k][dv] -> 8192 + (k>>5)*1024 + a*256 + ((dv^a)<<3) + (k&7)
      {
        const int a = (l & 31) >> 3, b = l & 7;
#pragma unroll
        for (int reg = 0; reg < 16; ++reg) {
          const int dv = (reg & 3) + 8 * (reg >> 2) + 4 * h;
          sAux[8192 + wv * 1024 + a * 256 + ((dv ^ a) << 3) + b] = (_Float16)vacc[reg];
        }
      }
      __syncthreads();   // K/VT visible

      // ---- flash over 8 k-tiles ----
      float mrun = -3e38f, lsum = 0.f;
      f32x16 oacc = zero16();
#pragma unroll 1
      for (int kt = 0; kt < 8; ++kt) {
        f32x16 sacc = zero16();
        sacc = MFMA32(*(const f16x8*)(sAux + kt * 1024 + l * 8), qf0, sacc);
        sacc = MFMA32(*(const f16x8*)(sAux + kt * 1024 + 512 + l * 8), qf1, sacc);
        float tm = sacc[0];
#pragma unroll
        for (int e = 1; e < 16; ++e) tm = fmaxf(tm, sacc[e]);
        tm = fmaxf(tm, crossHalf(tm, h));
        const float mnew = fmaxf(mrun, tm);
        const float corr = __expf(mrun - mnew);
        float ts = 0.f;
#pragma unroll
        for (int e = 0; e < 16; ++e) {
          const float ev = __expf(sacc[e] - mnew);
          sacc[e] = ev;
          ts += ev;
        }
        ts += crossHalf(ts, h);
        lsum = fmaf(lsum, corr, ts);
#pragma unroll
        for (int e = 0; e < 16; ++e) oacc[e] *= corr;
        f16x8 pf0 = t1frag(sacc, 0), pf1 = t1frag(sacc, 1);
        // VT A-frag reads: a_r = 2f + h; addr conflict-free (32x16B per 512B region)
        const int ar0 = h, ar1 = 2 + h;
        f16x8 va0 = *(const f16x8*)(sAux + 8192 + kt * 1024 + ar0 * 256 + (((l & 31) ^ ar0) << 3));
        f16x8 va1 = *(const f16x8*)(sAux + 8192 + kt * 1024 + ar1 * 256 + (((l & 31) ^ ar1) << 3));
        oacc = MFMA32(va0, pf0, oacc);
        oacc = MFMA32(va1, pf1, oacc);
        mrun = mnew;
      }
      const float linv = 1.f / lsum;
#pragma unroll
      for (int e = 0; e < 16; ++e) oacc[e] *= linv;
      f16x8 of0 = t1frag(oacc, 0), of1 = t1frag(oacc, 1);

      // ---- Z^T = ow[:,hd*32:+32] @ O^T (+ob at hd==0), residual into sX ----
#pragma unroll 1
      for (int dt = 0; dt < 4; ++dt) {
        f32x16 zacc = (hd == 0) ? bias16(ob1, dt * 32, h) : zero16();
        f16x8 a0 = *(const f16x8*)(p.wow + (dt * 32 + (l & 31)) * 128 + hd * 32 + h * 8);
        f16x8 a1 = *(const f16x8*)(p.wow + (dt * 32 + (l & 31)) * 128 + hd * 32 + 16 + h * 8);
        zacc = MFMA32(a0, of0, zacc);
        zacc = MFMA32(a1, of1, zacc);
        flush16(sX, row, dt * 32, h, zacc);
      }
      // next head's top barrier protects sAux
    }
  }

  // ---- FFN1 ----
  ffn_phase(sX, sAux, t, strip, l, p.n2a + 128, p.n2b + 128,
            p.wff + 131072, p.b1 + 512, p.wff + 196608, p.b2 + 128);

  // ---- final norm + output projection (r8-verbatim, HW-verified) ----
  {
    const int r = strip + (l & 31), hf = l >> 5;
    float sum = 0.f, sq = 0.f;
#pragma unroll
    for (int c = 0; c < 16; ++c) {
      f32x4 v = *(const f32x4*)&sX[XF(r, hf * 64 + c * 4)];
#pragma unroll
      for (int e = 0; e < 4; ++e) { sum += v[e]; sq = fmaf(v[e], v[e], sq); }
    }
    sum += __shfl_xor(sum, 32);
    sq  += __shfl_xor(sq, 32);
    float mu = sum * (1.f / 128.f);
    float var = fmaf(-sum, mu, sq) * (1.f / 127.f);
    float inv = 1.f / (sqrtf(var) + 1e-6f);
    float os = 0.f;
#pragma unroll
    for (int c = 0; c < 16; ++c) {
      f32x4 x  = *(const f32x4*)&sX[XF(r, hf * 64 + c * 4)];
      f32x4 fa = *(const f32x4*)&p.fna[hf * 64 + c * 4];
      f32x4 fb = *(const f32x4*)&p.fnb[hf * 64 + c * 4];
      f32x4 wo = *(const f32x4*)&p.out_w[hf * 64 + c * 4];
#pragma unroll
      for (int e = 0; e < 4; ++e)
        os = fmaf(fmaf(fa[e] * inv, x[e] - mu, fb[e]), wo[e], os);
    }
    os += __shfl_xor(os, 32);
    if (l < 32) p.out[i * 256 + r] = os + p.out_b[0];
  }
}

// ---------------- host ----------------
extern "C" void kernel_launch(void* const* d_in, const int* in_sizes, int n_in,
                              void* d_out, int out_size, void* d_ws, size_t ws_size,
                              hipStream_t stream) {
  float* x0 = (float*)d_ws;                           // 32768 f32
  float* a0 = x0 + 32768;                             // 32768 f32
  _Float16* W16 = (_Float16*)((char*)d_ws + 262144);  // 327680 halves

  P0 p0;
  p0.qw = (const float*)d_in[8];  p0.kw = (const float*)d_in[10];
  p0.vw = (const float*)d_in[12]; p0.ow = (const float*)d_in[14];
  p0.w1 = (const float*)d_in[20]; p0.w2 = (const float*)d_in[22];
  p0.dst = W16;
  convblk<<<dim3(1280), dim3(256), 0, stream>>>(p0);

  P1 p1;
  p1.src  = (const float*)d_in[0];
  p1.t    = (const int*)  d_in[1];
  p1.fc_w = (const float*)d_in[2];  p1.fc_b = (const float*)d_in[3];
  p1.gc_w = (const float*)d_in[4];  p1.gc_b = (const float*)d_in[5];
  p1.ln_w = (const float*)d_in[6];  p1.ln_b = (const float*)d_in[7];
  p1.n1a  = (const float*)d_in[16]; p1.n1b  = (const float*)d_in[17];
  p1.vw   = (const float*)d_in[12]; p1.vb   = (const float*)d_in[13];
  p1.ow   = (const float*)d_in[14]; p1.ob   = (const float*)d_in[15];
  p1.x0 = x0; p1.a0 = a0;
  prep<<<dim3(128), dim3(256), 0, stream>>>(p1);

  P2 p2;
  p2.x0 = x0; p2.a0 = a0;
  p2.wff  = W16;
  p2.wkvq = W16 + 262144;
  p2.wow  = W16 + 311296;
  p2.qb = (const float*)d_in[9];  p2.kb = (const float*)d_in[11];
  p2.vb = (const float*)d_in[13]; p2.ob = (const float*)d_in[15];
  p2.n1a = (const float*)d_in[16]; p2.n1b = (const float*)d_in[17];
  p2.n2a = (const float*)d_in[18]; p2.n2b = (const float*)d_in[19];
  p2.b1 = (const float*)d_in[21];  p2.b2 = (const float*)d_in[23];
  p2.fna = (const float*)d_in[24]; p2.fnb = (const float*)d_in[25];
  p2.out_w = (const float*)d_in[26]; p2.out_b = (const float*)d_in[27];
  p2.out = (float*)d_out;
  batchk<<<dim3(256), dim3(512), 0, stream>>>(p2);
}